// Round 1
// baseline (72.200 us; speedup 1.0000x reference)
//
#include <hip/hip_runtime.h>

#define PAD 8

// out[n,c,y,x] = x[n, c, clamp(y+sy-8,0,H-1), clamp(x+sx-8,0,W-1)]
// where (sx, sy) = shift[n] (raw, in [0,16]).
//
// Layout: one 256-thread block handles 8 rows of W=128 floats.
// Each thread: 4 clamped scalar loads (coalesced across lanes), 1 float4 store.
__global__ __launch_bounds__(256) void shift_aug_kernel(
    const float* __restrict__ x,
    const int* __restrict__ shift,
    float* __restrict__ out,
    int nRows /* N*C*H */, int Cc) {
  constexpr int H = 128, W = 128;

  int row = blockIdx.x * 8 + (threadIdx.x >> 5);  // row over N*C*H
  if (row >= nRows) return;
  int t = threadIdx.x & 31;                        // 32 float4 lanes per row

  int y  = row & (H - 1);
  int nc = row >> 7;            // row / H
  int n  = nc / Cc;             // sample index

  int sx = shift[2 * n + 0] - PAD;
  int sy = shift[2 * n + 1] - PAD;

  int ysrc = min(max(y + sy, 0), H - 1);
  const float* __restrict__ in_row = x + ((long long)nc * H + ysrc) * W;

  int x0 = t * 4 + sx;
  float4 v;
  v.x = in_row[min(max(x0 + 0, 0), W - 1)];
  v.y = in_row[min(max(x0 + 1, 0), W - 1)];
  v.z = in_row[min(max(x0 + 2, 0), W - 1)];
  v.w = in_row[min(max(x0 + 3, 0), W - 1)];

  reinterpret_cast<float4*>(out + (long long)row * W)[t] = v;
}

extern "C" void kernel_launch(void* const* d_in, const int* in_sizes, int n_in,
                              void* d_out, int out_size, void* d_ws, size_t ws_size,
                              hipStream_t stream) {
  const float* x     = (const float*)d_in[0];
  const int*   shift = (const int*)d_in[1];
  float*       out   = (float*)d_out;

  const int C = 9, H = 128;
  int N = in_sizes[1] / 2;          // shift is (N,1,1,2) int32
  int nRows = N * C * H;            // 294912
  int blocks = (nRows + 7) / 8;     // 8 rows per block

  hipLaunchKernelGGL(shift_aug_kernel, dim3(blocks), dim3(256), 0, stream,
                     x, shift, out, nRows, C);
}

// Round 2
// 50.915 us; speedup vs baseline: 1.4181x; 1.4181x over previous
//
#include <hip/hip_runtime.h>

#define PAD 8

// out[n,c,y,x] = x[n, c, clamp(y+sy,0,127), clamp(x+sx,0,127)], (sx,sy)=shift[n]-8.
//
// Block = 256 threads, handles 32 consecutive rows (4 tiles x 8 rows) of the
// flattened (N*C*H) row space. 32 | 128 so all rows in a block share nc and n,
// hence a single uniform (sx, sy).
//
// Phase 1: stage rows into LDS with ALIGNED float4 global loads (y-clamp here).
// Phase 2: x-shift via clamped scalar LDS reads, aligned float4 global stores.
// LDS pitch 130 floats: keeps float2 stores 8B-aligned, cuts read-phase bank
// conflicts from 8-way to 4-way.
__global__ __launch_bounds__(256) void shift_aug_kernel(
    const float* __restrict__ x,
    const int* __restrict__ shift,
    float* __restrict__ out,
    int C) {
  constexpr int H = 128, W = 128;
  constexpr int TILES = 4, ROWS = 8;
  constexpr int PITCH = W + 2;  // 130

  __shared__ float lds[TILES][ROWS][PITCH];  // 16.6 KB

  const int r = threadIdx.x >> 5;   // 0..7: row within tile
  const int t = threadIdx.x & 31;   // float4 lane within row

  const int base = blockIdx.x * (TILES * ROWS);   // first row of block
  const int nc = base >> 7;                       // row / 128
  const int n  = nc / C;

  const int sx = shift[2 * n + 0] - PAD;
  const int sy = shift[2 * n + 1] - PAD;

  const int ybase = base & (H - 1);               // y of first row in block

  const float* __restrict__ xin = x + (size_t)nc * H * W;

  // ---- stage: aligned float4 loads, y-clamped source rows ----
#pragma unroll
  for (int k = 0; k < TILES; ++k) {
    int y = ybase + k * ROWS + r;
    int ysrc = min(max(y + sy, 0), H - 1);
    float4 v = reinterpret_cast<const float4*>(xin + ysrc * W)[t];
    float2* dst = reinterpret_cast<float2*>(&lds[k][r][0]) + 2 * t;
    dst[0] = make_float2(v.x, v.y);
    dst[1] = make_float2(v.z, v.w);
  }
  __syncthreads();

  // ---- shift in x, aligned float4 stores ----
  const int x0 = 4 * t + sx;
  const int i0 = min(max(x0 + 0, 0), W - 1);
  const int i1 = min(max(x0 + 1, 0), W - 1);
  const int i2 = min(max(x0 + 2, 0), W - 1);
  const int i3 = min(max(x0 + 3, 0), W - 1);

#pragma unroll
  for (int k = 0; k < TILES; ++k) {
    float4 o;
    o.x = lds[k][r][i0];
    o.y = lds[k][r][i1];
    o.z = lds[k][r][i2];
    o.w = lds[k][r][i3];
    size_t row = (size_t)base + k * ROWS + r;
    reinterpret_cast<float4*>(out + row * W)[t] = o;
  }
}

extern "C" void kernel_launch(void* const* d_in, const int* in_sizes, int n_in,
                              void* d_out, int out_size, void* d_ws, size_t ws_size,
                              hipStream_t stream) {
  const float* x     = (const float*)d_in[0];
  const int*   shift = (const int*)d_in[1];
  float*       out   = (float*)d_out;

  const int C = 9, H = 128;
  int N = in_sizes[1] / 2;            // shift is (N,1,1,2) int32
  int nRows = N * C * H;              // 294912
  int blocks = nRows / 32;            // 9216 blocks, 32 rows each

  hipLaunchKernelGGL(shift_aug_kernel, dim3(blocks), dim3(256), 0, stream,
                     x, shift, out, C);
}

// Round 4
// 48.129 us; speedup vs baseline: 1.5001x; 1.0579x over previous
//
#include <hip/hip_runtime.h>

#define PAD 8

typedef float f32x4 __attribute__((ext_vector_type(4)));

// out[n,c,y,x] = x[n, c, clamp(y+sy,0,127), clamp(x+sx,0,127)], (sx,sy)=shift[n]-8.
//
// R2 structure (LDS-staged aligned read / x-shift in LDS / aligned float4
// store) + non-temporal output stores so the 151 MB write stream doesn't
// evict the 151 MB input from the 256 MB Infinity Cache. Stores use a native
// clang ext_vector (HIP_vector_type is rejected by the builtin).
__global__ __launch_bounds__(256) void shift_aug_kernel(
    const float* __restrict__ x,
    const int* __restrict__ shift,
    float* __restrict__ out,
    int C) {
  constexpr int H = 128, W = 128;
  constexpr int TILES = 4, ROWS = 8;
  constexpr int PITCH = W + 2;  // 130

  __shared__ float lds[TILES][ROWS][PITCH];  // 16.6 KB

  const int r = threadIdx.x >> 5;   // 0..7: row within tile
  const int t = threadIdx.x & 31;   // float4 lane within row

  const int base = blockIdx.x * (TILES * ROWS);   // first row of block
  const int nc = base >> 7;                       // row / 128
  const int n  = nc / C;

  const int sx = shift[2 * n + 0] - PAD;
  const int sy = shift[2 * n + 1] - PAD;

  const int ybase = base & (H - 1);               // y of first row in block

  const float* __restrict__ xin = x + (size_t)nc * H * W;

  // ---- stage: aligned float4 loads, y-clamped source rows ----
#pragma unroll
  for (int k = 0; k < TILES; ++k) {
    int y = ybase + k * ROWS + r;
    int ysrc = min(max(y + sy, 0), H - 1);
    float4 v = reinterpret_cast<const float4*>(xin + ysrc * W)[t];
    float2* dst = reinterpret_cast<float2*>(&lds[k][r][0]) + 2 * t;
    dst[0] = make_float2(v.x, v.y);
    dst[1] = make_float2(v.z, v.w);
  }
  __syncthreads();

  // ---- shift in x, aligned float4 NON-TEMPORAL stores ----
  const int x0 = 4 * t + sx;
  const int i0 = min(max(x0 + 0, 0), W - 1);
  const int i1 = min(max(x0 + 1, 0), W - 1);
  const int i2 = min(max(x0 + 2, 0), W - 1);
  const int i3 = min(max(x0 + 3, 0), W - 1);

#pragma unroll
  for (int k = 0; k < TILES; ++k) {
    f32x4 o;
    o.x = lds[k][r][i0];
    o.y = lds[k][r][i1];
    o.z = lds[k][r][i2];
    o.w = lds[k][r][i3];
    size_t row = (size_t)base + k * ROWS + r;
    __builtin_nontemporal_store(o, reinterpret_cast<f32x4*>(out + row * W) + t);
  }
}

extern "C" void kernel_launch(void* const* d_in, const int* in_sizes, int n_in,
                              void* d_out, int out_size, void* d_ws, size_t ws_size,
                              hipStream_t stream) {
  const float* x     = (const float*)d_in[0];
  const int*   shift = (const int*)d_in[1];
  float*       out   = (float*)d_out;

  const int C = 9, H = 128;
  int N = in_sizes[1] / 2;            // shift is (N,1,1,2) int32
  int nRows = N * C * H;              // 294912
  int blocks = nRows / 32;            // 9216 blocks, 32 rows each

  hipLaunchKernelGGL(shift_aug_kernel, dim3(blocks), dim3(256), 0, stream,
                     x, shift, out, C);
}